// Round 5
// baseline (1209.904 us; speedup 1.0000x reference)
//
#include <hip/hip_runtime.h>
#include <hip/hip_cooperative_groups.h>
#include <math.h>

namespace cg = cooperative_groups;

#define DIM 128
#define GRID 1024
#define TPB  256

// ======================= ONE cooperative kernel: all phases =======================
__global__ __launch_bounds__(TPB, 4) void fused_kernel(
    const float* __restrict__ inputs, const float* __restrict__ old_act,
    const int* __restrict__ fields,
    const int* __restrict__ sub_rows, const int* __restrict__ sub_cols,
    const float* __restrict__ sub_vals, int e_sub,
    const int* __restrict__ sup_rows, const int* __restrict__ sup_cols,
    const float* __restrict__ sup_vals, int e_sup,
    int* __restrict__ cnt, int* __restrict__ tmp, int* __restrict__ offs,
    int* __restrict__ bsum, int* __restrict__ boff, int2* __restrict__ pk,
    float* __restrict__ partials, float* __restrict__ diff, int use_diff,
    float* __restrict__ out, int nrows, int n)
{
    cg::grid_group grid = cg::this_grid();
    const int tid      = blockIdx.x * TPB + threadIdx.x;
    const int nthreads = GRID * TPB;
    const int m        = 2 * nrows;
    const int e_tot    = e_sub + e_sup;
    const int nblkA    = (m + TPB - 1) / TPB;
    const int lane     = threadIdx.x & 63;
    const int wv       = threadIdx.x >> 6;

    __shared__ int   s_scan[TPB];
    __shared__ float s_red[3][4];

    // ---- P0: zero cnt ----
    for (int i = tid; i < m; i += nthreads) cnt[i] = 0;
    grid.sync();

    // ---- P1: sim partials + diff precompute + row histogram ----
    {
        float dot = 0.f, nx = 0.f, ny = 0.f;
        int n2 = n / 2;
        for (int i = tid; i < n2; i += nthreads) {
            int idx = i * 2;
            int b = idx >> 7, d = idx & (DIM - 1);
            float2 x = *(const float2*)(inputs + idx);
            int f = fields[b];
            float2 y = *(const float2*)(old_act + (size_t)f * DIM + d);
            dot += x.x * y.x + x.y * y.y;
            nx  += x.x * x.x + x.y * x.y;
            ny  += y.x * y.x + y.y * y.y;
            if (use_diff)
                *(float2*)(diff + idx) = make_float2(x.x - y.x, x.y - y.y);
        }
        for (int off = 32; off > 0; off >>= 1) {
            dot += __shfl_down(dot, off, 64);
            nx  += __shfl_down(nx,  off, 64);
            ny  += __shfl_down(ny,  off, 64);
        }
        if (lane == 0) { s_red[0][wv] = dot; s_red[1][wv] = nx; s_red[2][wv] = ny; }
        __syncthreads();
        if (threadIdx.x == 0) {
            float D = 0.f, NX = 0.f, NY = 0.f;
            for (int w = 0; w < 4; ++w) { D += s_red[0][w]; NX += s_red[1][w]; NY += s_red[2][w]; }
            partials[blockIdx.x * 3 + 0] = D;
            partials[blockIdx.x * 3 + 1] = NX;
            partials[blockIdx.x * 3 + 2] = NY;
        }
        for (int i = tid; i < e_tot; i += nthreads) {
            int r = (i < e_sub) ? sub_rows[i] : (nrows + sup_rows[i - e_sub]);
            atomicAdd(&cnt[r], 1);
        }
    }
    grid.sync();

    // ---- P2: per-block scan of cnt (blocks < nblkA) ----
    if (blockIdx.x < nblkA) {
        int i = blockIdx.x * TPB + threadIdx.x;
        int v = (i < m) ? cnt[i] : 0;
        s_scan[threadIdx.x] = v;
        __syncthreads();
        for (int d = 1; d < TPB; d <<= 1) {
            int t = (threadIdx.x >= (unsigned)d) ? s_scan[threadIdx.x - d] : 0;
            __syncthreads();
            s_scan[threadIdx.x] += t;
            __syncthreads();
        }
        if (i < m) tmp[i] = s_scan[threadIdx.x] - v;     // exclusive within block
        if (threadIdx.x == TPB - 1) bsum[blockIdx.x] = s_scan[TPB - 1];
    }
    grid.sync();

    // ---- P3: block 0 — wave 0 scans bsum -> boff; wave 1 finalizes sim ----
    if (blockIdx.x == 0) {
        if (wv == 0) {
            int ipl = (nblkA + 63) / 64;
            int base = lane * ipl;
            int lanesum = 0;
            for (int k = 0; k < ipl; ++k) {
                int idx = base + k;
                if (idx < nblkA) lanesum += bsum[idx];
            }
            int incl = lanesum;
            for (int off = 1; off < 64; off <<= 1) {
                int t = __shfl_up(incl, off, 64);
                if (lane >= off) incl += t;
            }
            int run = incl - lanesum;                     // exclusive
            for (int k = 0; k < ipl; ++k) {
                int idx = base + k;
                if (idx < nblkA) { boff[idx] = run; run += bsum[idx]; }
            }
        } else if (wv == 1) {
            double dot = 0.0, nx = 0.0, ny = 0.0;
            for (int i = lane; i < GRID; i += 64) {
                dot += (double)partials[i * 3 + 0];
                nx  += (double)partials[i * 3 + 1];
                ny  += (double)partials[i * 3 + 2];
            }
            for (int off = 32; off > 0; off >>= 1) {
                dot += __shfl_down(dot, off, 64);
                nx  += __shfl_down(nx,  off, 64);
                ny  += __shfl_down(ny,  off, 64);
            }
            if (lane == 0)
                out[n] = (float)(dot / (sqrt(nx) * sqrt(ny)));
        }
    }
    grid.sync();

    // ---- P4: offs/cur from tmp + boff ----
    for (int i = tid; i < m; i += nthreads) {
        int o = tmp[i] + boff[i >> 8];
        offs[i] = o;
        tmp[i]  = o;          // tmp now serves as cur
    }
    if (tid == 0) offs[m] = e_tot;
    grid.sync();

    // ---- P5: scatter edges into row buckets ----
    for (int i = tid; i < e_tot; i += nthreads) {
        int r, c; float v;
        if (i < e_sub) {
            r = sub_rows[i]; c = sub_cols[i]; v = sub_vals[i];
        } else {
            int k = i - e_sub;
            r = nrows + sup_rows[k]; c = sup_cols[k]; v = sup_vals[k];
        }
        int pos = atomicAdd(&tmp[r], 1);
        pk[pos] = make_int2(c, __float_as_int(v));
    }
    grid.sync();

    // ---- P6: per-row accumulate (one wave per row, grid-stride) ----
    {
        const int gwid   = tid >> 6;
        const int nwaves = nthreads >> 6;
        const int d0     = lane * 2;
        for (int r = gwid; r < nrows; r += nwaves) {
            float a0 = 0.f, a1 = 0.f;
            int b = offs[r], e = offs[r + 1];
            if (use_diff) {
                for (int j = b; j < e; ++j) {
                    int2 p = pk[j];
                    int c = p.x; float v = __int_as_float(p.y);
                    float2 xd = *(const float2*)(diff + (size_t)c * DIM + d0);
                    a0 += v * xd.x;
                    a1 += v * xd.y;
                }
            } else {
                for (int j = b; j < e; ++j) {
                    int2 p = pk[j];
                    int c = p.x; float v = __int_as_float(p.y);
                    int f = fields[c];
                    float2 x = *(const float2*)(inputs  + (size_t)c * DIM + d0);
                    float2 y = *(const float2*)(old_act + (size_t)f * DIM + d0);
                    a0 += v * (x.x - y.x);
                    a1 += v * (x.y - y.y);
                }
            }
            b = offs[nrows + r]; e = offs[nrows + r + 1];
            for (int j = b; j < e; ++j) {
                int2 p = pk[j];
                int c = p.x; float v = __int_as_float(p.y);
                float2 y = *(const float2*)(old_act + (size_t)c * DIM + d0);
                a0 += v * y.x;
                a1 += v * y.y;
            }
            *(float2*)(out + (size_t)r * DIM + d0) = make_float2(a0, a1);
        }
    }
}

// ======================= fallback: round-4 multi-kernel path =======================
__global__ void prep_kernel(const float* __restrict__ inputs,
                            const float* __restrict__ old_act,
                            const int* __restrict__ fields,
                            const int* __restrict__ sub_rows, int e_sub,
                            const int* __restrict__ sup_rows, int e_sup,
                            int* __restrict__ cnt, float* __restrict__ partials,
                            int nrows, int n2) {
    int tid = blockIdx.x * blockDim.x + threadIdx.x;
    int stride = gridDim.x * blockDim.x;
    float dot = 0.f, nx = 0.f, ny = 0.f;
    for (int i = tid; i < n2; i += stride) {
        int idx = i * 2;
        int b = idx >> 7, d = idx & (DIM - 1);
        float2 x = *(const float2*)(inputs + idx);
        int f = fields[b];
        float2 y = *(const float2*)(old_act + (size_t)f * DIM + d);
        dot += x.x * y.x + x.y * y.y;
        nx  += x.x * x.x + x.y * x.y;
        ny  += y.x * y.x + y.y * y.y;
    }
    int e_tot = e_sub + e_sup;
    for (int i = tid; i < e_tot; i += stride) {
        int r = (i < e_sub) ? sub_rows[i] : (nrows + sup_rows[i - e_sub]);
        atomicAdd(&cnt[r], 1);
    }
    for (int off = 32; off > 0; off >>= 1) {
        dot += __shfl_down(dot, off, 64);
        nx  += __shfl_down(nx,  off, 64);
        ny  += __shfl_down(ny,  off, 64);
    }
    __shared__ float s[3][4];
    int lane = threadIdx.x & 63, wv = threadIdx.x >> 6;
    if (lane == 0) { s[0][wv] = dot; s[1][wv] = nx; s[2][wv] = ny; }
    __syncthreads();
    if (threadIdx.x == 0) {
        float D = 0.f, NX = 0.f, NY = 0.f;
        for (int w = 0; w < 4; ++w) { D += s[0][w]; NX += s[1][w]; NY += s[2][w]; }
        partials[blockIdx.x * 3 + 0] = D;
        partials[blockIdx.x * 3 + 1] = NX;
        partials[blockIdx.x * 3 + 2] = NY;
    }
}

__global__ void finalize_kernel(const float* __restrict__ partials, int np,
                                float* __restrict__ out_sim) {
    double dot = 0.0, nx = 0.0, ny = 0.0;
    for (int i = threadIdx.x; i < np; i += 64) {
        dot += (double)partials[i * 3 + 0];
        nx  += (double)partials[i * 3 + 1];
        ny  += (double)partials[i * 3 + 2];
    }
    for (int off = 32; off > 0; off >>= 1) {
        dot += __shfl_down(dot, off, 64);
        nx  += __shfl_down(nx,  off, 64);
        ny  += __shfl_down(ny,  off, 64);
    }
    if (threadIdx.x == 0)
        *out_sim = (float)(dot / (sqrt(nx) * sqrt(ny)));
}

__global__ void scanA_kernel(const int* __restrict__ cnt, int* __restrict__ tmp,
                             int* __restrict__ bsum, int m) {
    __shared__ int s[256];
    int i = blockIdx.x * 256 + threadIdx.x;
    int v = (i < m) ? cnt[i] : 0;
    s[threadIdx.x] = v;
    __syncthreads();
    for (int d = 1; d < 256; d <<= 1) {
        int t = (threadIdx.x >= (unsigned)d) ? s[threadIdx.x - d] : 0;
        __syncthreads();
        s[threadIdx.x] += t;
        __syncthreads();
    }
    if (i < m) tmp[i] = s[threadIdx.x] - v;
    if (threadIdx.x == 255) bsum[blockIdx.x] = s[255];
}

__global__ void scanB_kernel(int* __restrict__ bsum, int* __restrict__ boff, int nb) {
    __shared__ int s[512];
    int v = (threadIdx.x < nb) ? bsum[threadIdx.x] : 0;
    s[threadIdx.x] = v;
    __syncthreads();
    for (int d = 1; d < 512; d <<= 1) {
        int t = (threadIdx.x >= (unsigned)d) ? s[threadIdx.x - d] : 0;
        __syncthreads();
        s[threadIdx.x] += t;
        __syncthreads();
    }
    if (threadIdx.x < nb) boff[threadIdx.x] = s[threadIdx.x] - v;
}

__global__ void scanC_kernel(const int* tmp, const int* __restrict__ boff,
                             int* __restrict__ off, int* cur, int m, int e_tot) {
    int i = blockIdx.x * 256 + threadIdx.x;
    if (i < m) {
        int o = tmp[i] + boff[i >> 8];
        off[i] = o;
        cur[i] = o;
    }
    if (i == 0) off[m] = e_tot;
}

__global__ void scatter_kernel(const int* __restrict__ sub_rows, const int* __restrict__ sub_cols,
                               const float* __restrict__ sub_vals, int e_sub,
                               const int* __restrict__ sup_rows, const int* __restrict__ sup_cols,
                               const float* __restrict__ sup_vals, int e_sup,
                               int* __restrict__ cur, int2* __restrict__ pk, int nrows) {
    int i = blockIdx.x * blockDim.x + threadIdx.x;
    int e_tot = e_sub + e_sup;
    if (i >= e_tot) return;
    int r, c; float v;
    if (i < e_sub) { r = sub_rows[i]; c = sub_cols[i]; v = sub_vals[i]; }
    else { int k = i - e_sub; r = nrows + sup_rows[k]; c = sup_cols[k]; v = sup_vals[k]; }
    int pos = atomicAdd(&cur[r], 1);
    pk[pos] = make_int2(c, __float_as_int(v));
}

__global__ void row_kernel(const int* __restrict__ off, const int2* __restrict__ pk,
                           const float* __restrict__ inputs, const float* __restrict__ old_act,
                           const int* __restrict__ fields, float* __restrict__ out, int nrows) {
    int wv = threadIdx.x >> 6, lane = threadIdx.x & 63;
    int r = blockIdx.x * (blockDim.x >> 6) + wv;
    if (r >= nrows) return;
    int d0 = lane * 2;
    float a0 = 0.f, a1 = 0.f;
    int b = off[r], e = off[r + 1];
    for (int j = b; j < e; ++j) {
        int2 p = pk[j];
        int c = p.x; float v = __int_as_float(p.y);
        int f = fields[c];
        float2 x = *(const float2*)(inputs  + (size_t)c * DIM + d0);
        float2 y = *(const float2*)(old_act + (size_t)f * DIM + d0);
        a0 += v * (x.x - y.x);
        a1 += v * (x.y - y.y);
    }
    b = off[nrows + r]; e = off[nrows + r + 1];
    for (int j = b; j < e; ++j) {
        int2 p = pk[j];
        int c = p.x; float v = __int_as_float(p.y);
        float2 y = *(const float2*)(old_act + (size_t)c * DIM + d0);
        a0 += v * y.x;
        a1 += v * y.y;
    }
    *(float2*)(out + (size_t)r * DIM + d0) = make_float2(a0, a1);
}

extern "C" void kernel_launch(void* const* d_in, const int* in_sizes, int n_in,
                              void* d_out, int out_size, void* d_ws, size_t ws_size,
                              hipStream_t stream) {
    const float* inputs   = (const float*)d_in[0];
    const float* old_act  = (const float*)d_in[1];
    const int*   fields   = (const int*)d_in[2];
    const int*   sub_rows = (const int*)d_in[3];
    const int*   sub_cols = (const int*)d_in[4];
    const float* sub_vals = (const float*)d_in[5];
    const int*   sup_rows = (const int*)d_in[6];
    const int*   sup_cols = (const int*)d_in[7];
    const float* sup_vals = (const float*)d_in[8];

    const int n     = in_sizes[0];       // BATCH * DIM
    const int nrows = n / DIM;           // BATCH
    const int e_sub = in_sizes[3];
    const int e_sup = in_sizes[6];
    const int e_tot = e_sub + e_sup;
    const int m     = 2 * nrows;
    const int nblkA = (m + 255) / 256;

    float* out = (float*)d_out;
    char*  ws  = (char*)d_ws;

    // ---- workspace layout ----
    size_t off_part = 0;                                      // f32[GRID*3]
    size_t off_cnt  = (GRID * 3 * 4 + 63) & ~(size_t)63;      // int[m]
    size_t off_tmp  = off_cnt + (size_t)m * 4;                // int[m] (cur alias)
    size_t off_offs = off_tmp + (size_t)m * 4;                // int[m+1]
    size_t off_bsum = off_offs + (size_t)(m + 1) * 4;         // int[1024]
    size_t off_boff = off_bsum + 4096;                        // int[1024]
    size_t off_pk   = (off_boff + 4096 + 7) & ~(size_t)7;     // int2[e_tot]
    size_t off_diff = off_pk + (size_t)e_tot * 8;             // f32[n]
    size_t need_base = off_diff;
    size_t need_diff = off_diff + (size_t)n * 4;

    float* partials = (float*)(ws + off_part);
    int*   cnt      = (int*)(ws + off_cnt);
    int*   tmp      = (int*)(ws + off_tmp);
    int*   offs     = (int*)(ws + off_offs);
    int*   bsum     = (int*)(ws + off_bsum);
    int*   boff     = (int*)(ws + off_boff);
    int2*  pk       = (int2*)(ws + off_pk);
    float* diff     = (float*)(ws + off_diff);

    bool fits = (ws_size >= need_base) && (nblkA <= 512) && (m <= GRID * TPB);
    int  use_diff = (ws_size >= need_diff) ? 1 : 0;

    hipError_t coop_err = hipErrorUnknown;
    if (fits) {
        void* args[] = {
            (void*)&inputs, (void*)&old_act, (void*)&fields,
            (void*)&sub_rows, (void*)&sub_cols, (void*)&sub_vals, (void*)&e_sub,
            (void*)&sup_rows, (void*)&sup_cols, (void*)&sup_vals, (void*)&e_sup,
            (void*)&cnt, (void*)&tmp, (void*)&offs, (void*)&bsum, (void*)&boff,
            (void*)&pk, (void*)&partials, (void*)&diff, (void*)&use_diff,
            (void*)&out, (void*)&nrows, (void*)&n
        };
        coop_err = hipLaunchCooperativeKernel((const void*)fused_kernel,
                                              dim3(GRID), dim3(TPB), args, 0, stream);
    }

    if (coop_err != hipSuccess && fits) {
        // fallback: round-4 multi-kernel pipeline
        hipMemsetAsync(cnt, 0, (size_t)m * 4, stream);
        prep_kernel<<<2048, 256, 0, stream>>>(inputs, old_act, fields,
                                              sub_rows, e_sub, sup_rows, e_sup,
                                              cnt, partials, nrows, n / 2);
        scanA_kernel<<<nblkA, 256, 0, stream>>>(cnt, tmp, bsum, m);
        scanB_kernel<<<1, 512, 0, stream>>>(bsum, boff, nblkA);
        scanC_kernel<<<nblkA, 256, 0, stream>>>(tmp, boff, offs, tmp, m, e_tot);
        scatter_kernel<<<(e_tot + 255) / 256, 256, 0, stream>>>(
            sub_rows, sub_cols, sub_vals, e_sub,
            sup_rows, sup_cols, sup_vals, e_sup, tmp, pk, nrows);
        row_kernel<<<(nrows + 3) / 4, 256, 0, stream>>>(offs, pk, inputs, old_act,
                                                        fields, out, nrows);
        finalize_kernel<<<1, 64, 0, stream>>>(partials, 2048, out + n);
    }
}

// Round 6
// 412.765 us; speedup vs baseline: 2.9312x; 2.9312x over previous
//
#include <hip/hip_runtime.h>
#include <math.h>

#define DIM 128
#define TPB 256
#define PREP_GRID 2048
#define SUB_CAP 32
#define SUP_CAP 64
#define OVER_MAX 65536

// ================= primary path =================
// prep: sim partials + diff precompute + single-pass bucket binning
__global__ void prep_bin_kernel(const float* __restrict__ inputs,
                                const float* __restrict__ old_act,
                                const int* __restrict__ fields,
                                const int* __restrict__ sub_rows, const int* __restrict__ sub_cols,
                                const float* __restrict__ sub_vals, int e_sub,
                                const int* __restrict__ sup_rows, const int* __restrict__ sup_cols,
                                const float* __restrict__ sup_vals, int e_sup,
                                int* __restrict__ cnt,            // [2*nrows] + over_cnt at [2*nrows]
                                int2* __restrict__ pk_sub, int2* __restrict__ pk_sup,
                                int4* __restrict__ over,
                                float* __restrict__ partials, float* __restrict__ diff,
                                int use_diff, int nrows, int n2) {
    int tid = blockIdx.x * blockDim.x + threadIdx.x;
    int stride = gridDim.x * blockDim.x;
    int* over_cnt = cnt + 2 * nrows;

    // sim + diff
    float dot = 0.f, nx = 0.f, ny = 0.f;
    for (int i = tid; i < n2; i += stride) {
        int idx = i * 2;
        int b = idx >> 7, d = idx & (DIM - 1);
        float2 x = *(const float2*)(inputs + idx);
        int f = fields[b];
        float2 y = *(const float2*)(old_act + (size_t)f * DIM + d);
        dot += x.x * y.x + x.y * y.y;
        nx  += x.x * x.x + x.y * x.y;
        ny  += y.x * y.x + y.y * y.y;
        if (use_diff)
            *(float2*)(diff + idx) = make_float2(x.x - y.x, x.y - y.y);
    }
    // binning
    int e_tot = e_sub + e_sup;
    for (int i = tid; i < e_tot; i += stride) {
        int r, c, sup; float v;
        if (i < e_sub) { r = sub_rows[i]; c = sub_cols[i]; v = sub_vals[i]; sup = 0; }
        else { int k = i - e_sub; r = sup_rows[k]; c = sup_cols[k]; v = sup_vals[k]; sup = 1; }
        int pos = atomicAdd(&cnt[sup ? nrows + r : r], 1);
        int cap = sup ? SUP_CAP : SUB_CAP;
        if (pos < cap) {
            int2* base = sup ? (pk_sup + (size_t)r * SUP_CAP) : (pk_sub + (size_t)r * SUB_CAP);
            base[pos] = make_int2(c, __float_as_int(v));
        } else {
            int op = atomicAdd(over_cnt, 1);
            if (op < OVER_MAX) over[op] = make_int4(r, c, __float_as_int(v), sup);
        }
    }
    // block-reduce sim
    for (int off = 32; off > 0; off >>= 1) {
        dot += __shfl_down(dot, off, 64);
        nx  += __shfl_down(nx,  off, 64);
        ny  += __shfl_down(ny,  off, 64);
    }
    __shared__ float s[3][4];
    int lane = threadIdx.x & 63, wv = threadIdx.x >> 6;
    if (lane == 0) { s[0][wv] = dot; s[1][wv] = nx; s[2][wv] = ny; }
    __syncthreads();
    if (threadIdx.x == 0) {
        float D = 0.f, NX = 0.f, NY = 0.f;
        for (int w = 0; w < 4; ++w) { D += s[0][w]; NX += s[1][w]; NY += s[2][w]; }
        partials[blockIdx.x * 3 + 0] = D;
        partials[blockIdx.x * 3 + 1] = NX;
        partials[blockIdx.x * 3 + 2] = NY;
    }
}

// row accumulate: one wave per row, 4-wide unrolled gathers
__global__ void row_bucket_kernel(const int* __restrict__ cnt,
                                  const int2* __restrict__ pk_sub, const int2* __restrict__ pk_sup,
                                  const float* __restrict__ diff,
                                  const float* __restrict__ inputs, const float* __restrict__ old_act,
                                  const int* __restrict__ fields,
                                  float* __restrict__ out, int nrows, int use_diff) {
    int wv = threadIdx.x >> 6, lane = threadIdx.x & 63;
    int r = blockIdx.x * (blockDim.x >> 6) + wv;
    if (r >= nrows) return;
    const int d0 = lane * 2;
    float a0 = 0.f, a1 = 0.f;

    // ---- sub edges ----
    {
        int e = cnt[r]; if (e > SUB_CAP) e = SUB_CAP;
        const int2* bp = pk_sub + (size_t)r * SUB_CAP;
        if (use_diff) {
            int j = 0;
            for (; j + 4 <= e; j += 4) {
                int2 p0 = bp[j], p1 = bp[j + 1], p2 = bp[j + 2], p3 = bp[j + 3];
                float2 y0 = *(const float2*)(diff + (size_t)p0.x * DIM + d0);
                float2 y1 = *(const float2*)(diff + (size_t)p1.x * DIM + d0);
                float2 y2 = *(const float2*)(diff + (size_t)p2.x * DIM + d0);
                float2 y3 = *(const float2*)(diff + (size_t)p3.x * DIM + d0);
                a0 += __int_as_float(p0.y) * y0.x; a1 += __int_as_float(p0.y) * y0.y;
                a0 += __int_as_float(p1.y) * y1.x; a1 += __int_as_float(p1.y) * y1.y;
                a0 += __int_as_float(p2.y) * y2.x; a1 += __int_as_float(p2.y) * y2.y;
                a0 += __int_as_float(p3.y) * y3.x; a1 += __int_as_float(p3.y) * y3.y;
            }
            for (; j < e; ++j) {
                int2 p = bp[j];
                float2 y = *(const float2*)(diff + (size_t)p.x * DIM + d0);
                a0 += __int_as_float(p.y) * y.x;
                a1 += __int_as_float(p.y) * y.y;
            }
        } else {
            for (int j = 0; j < e; ++j) {
                int2 p = bp[j];
                int c = p.x; float v = __int_as_float(p.y);
                int f = fields[c];
                float2 x = *(const float2*)(inputs  + (size_t)c * DIM + d0);
                float2 y = *(const float2*)(old_act + (size_t)f * DIM + d0);
                a0 += v * (x.x - y.x);
                a1 += v * (x.y - y.y);
            }
        }
    }
    // ---- sup edges ----
    {
        int e = cnt[nrows + r]; if (e > SUP_CAP) e = SUP_CAP;
        const int2* bp = pk_sup + (size_t)r * SUP_CAP;
        int j = 0;
        for (; j + 4 <= e; j += 4) {
            int2 p0 = bp[j], p1 = bp[j + 1], p2 = bp[j + 2], p3 = bp[j + 3];
            float2 y0 = *(const float2*)(old_act + (size_t)p0.x * DIM + d0);
            float2 y1 = *(const float2*)(old_act + (size_t)p1.x * DIM + d0);
            float2 y2 = *(const float2*)(old_act + (size_t)p2.x * DIM + d0);
            float2 y3 = *(const float2*)(old_act + (size_t)p3.x * DIM + d0);
            a0 += __int_as_float(p0.y) * y0.x; a1 += __int_as_float(p0.y) * y0.y;
            a0 += __int_as_float(p1.y) * y1.x; a1 += __int_as_float(p1.y) * y1.y;
            a0 += __int_as_float(p2.y) * y2.x; a1 += __int_as_float(p2.y) * y2.y;
            a0 += __int_as_float(p3.y) * y3.x; a1 += __int_as_float(p3.y) * y3.y;
        }
        for (; j < e; ++j) {
            int2 p = bp[j];
            float2 y = *(const float2*)(old_act + (size_t)p.x * DIM + d0);
            a0 += __int_as_float(p.y) * y.x;
            a1 += __int_as_float(p.y) * y.y;
        }
    }
    *(float2*)(out + (size_t)r * DIM + d0) = make_float2(a0, a1);
}

// tail: sim finalize (block 0, wave 0) + overflow edges (all threads)
__global__ void tail_kernel(const float* __restrict__ partials, int np,
                            const int* __restrict__ cnt, const int4* __restrict__ over,
                            const float* __restrict__ diff,
                            const float* __restrict__ inputs, const float* __restrict__ old_act,
                            const int* __restrict__ fields,
                            float* __restrict__ out, int nrows, int n, int use_diff) {
    if (blockIdx.x == 0 && threadIdx.x < 64) {
        double dot = 0.0, nx = 0.0, ny = 0.0;
        for (int i = threadIdx.x; i < np; i += 64) {
            dot += (double)partials[i * 3 + 0];
            nx  += (double)partials[i * 3 + 1];
            ny  += (double)partials[i * 3 + 2];
        }
        for (int off = 32; off > 0; off >>= 1) {
            dot += __shfl_down(dot, off, 64);
            nx  += __shfl_down(nx,  off, 64);
            ny  += __shfl_down(ny,  off, 64);
        }
        if (threadIdx.x == 0)
            out[n] = (float)(dot / (sqrt(nx) * sqrt(ny)));
    }
    int no = cnt[2 * nrows]; if (no > OVER_MAX) no = OVER_MAX;
    int tid = blockIdx.x * blockDim.x + threadIdx.x;
    int stride = gridDim.x * blockDim.x;
    for (int i = tid; i < no; i += stride) {
        int4 t = over[i];
        int r = t.x, c = t.y, sup = t.w;
        float v = __int_as_float(t.z);
        for (int d = 0; d < DIM; ++d) {
            float term;
            if (sup) term = old_act[(size_t)c * DIM + d];
            else if (use_diff) term = diff[(size_t)c * DIM + d];
            else term = inputs[(size_t)c * DIM + d] - old_act[(size_t)fields[c] * DIM + d];
            atomicAdd(&out[(size_t)r * DIM + d], v * term);
        }
    }
}

// ================= fallback: round-4 scan pipeline (proven) =================
__global__ void prep4_kernel(const float* __restrict__ inputs, const float* __restrict__ old_act,
                             const int* __restrict__ fields,
                             const int* __restrict__ sub_rows, int e_sub,
                             const int* __restrict__ sup_rows, int e_sup,
                             int* __restrict__ cnt, float* __restrict__ partials,
                             int nrows, int n2) {
    int tid = blockIdx.x * blockDim.x + threadIdx.x;
    int stride = gridDim.x * blockDim.x;
    float dot = 0.f, nx = 0.f, ny = 0.f;
    for (int i = tid; i < n2; i += stride) {
        int idx = i * 2;
        int b = idx >> 7, d = idx & (DIM - 1);
        float2 x = *(const float2*)(inputs + idx);
        int f = fields[b];
        float2 y = *(const float2*)(old_act + (size_t)f * DIM + d);
        dot += x.x * y.x + x.y * y.y;
        nx  += x.x * x.x + x.y * x.y;
        ny  += y.x * y.x + y.y * y.y;
    }
    int e_tot = e_sub + e_sup;
    for (int i = tid; i < e_tot; i += stride) {
        int r = (i < e_sub) ? sub_rows[i] : (nrows + sup_rows[i - e_sub]);
        atomicAdd(&cnt[r], 1);
    }
    for (int off = 32; off > 0; off >>= 1) {
        dot += __shfl_down(dot, off, 64);
        nx  += __shfl_down(nx,  off, 64);
        ny  += __shfl_down(ny,  off, 64);
    }
    __shared__ float s[3][4];
    int lane = threadIdx.x & 63, wv = threadIdx.x >> 6;
    if (lane == 0) { s[0][wv] = dot; s[1][wv] = nx; s[2][wv] = ny; }
    __syncthreads();
    if (threadIdx.x == 0) {
        float D = 0.f, NX = 0.f, NY = 0.f;
        for (int w = 0; w < 4; ++w) { D += s[0][w]; NX += s[1][w]; NY += s[2][w]; }
        partials[blockIdx.x * 3 + 0] = D;
        partials[blockIdx.x * 3 + 1] = NX;
        partials[blockIdx.x * 3 + 2] = NY;
    }
}

__global__ void finalize4_kernel(const float* __restrict__ partials, int np,
                                 float* __restrict__ out_sim) {
    double dot = 0.0, nx = 0.0, ny = 0.0;
    for (int i = threadIdx.x; i < np; i += 64) {
        dot += (double)partials[i * 3 + 0];
        nx  += (double)partials[i * 3 + 1];
        ny  += (double)partials[i * 3 + 2];
    }
    for (int off = 32; off > 0; off >>= 1) {
        dot += __shfl_down(dot, off, 64);
        nx  += __shfl_down(nx,  off, 64);
        ny  += __shfl_down(ny,  off, 64);
    }
    if (threadIdx.x == 0)
        *out_sim = (float)(dot / (sqrt(nx) * sqrt(ny)));
}

__global__ void scanA_kernel(const int* __restrict__ cnt, int* __restrict__ tmp,
                             int* __restrict__ bsum, int m) {
    __shared__ int s[256];
    int i = blockIdx.x * 256 + threadIdx.x;
    int v = (i < m) ? cnt[i] : 0;
    s[threadIdx.x] = v;
    __syncthreads();
    for (int d = 1; d < 256; d <<= 1) {
        int t = (threadIdx.x >= (unsigned)d) ? s[threadIdx.x - d] : 0;
        __syncthreads();
        s[threadIdx.x] += t;
        __syncthreads();
    }
    if (i < m) tmp[i] = s[threadIdx.x] - v;
    if (threadIdx.x == 255) bsum[blockIdx.x] = s[255];
}

__global__ void scanB_kernel(int* __restrict__ bsum, int* __restrict__ boff, int nb) {
    __shared__ int s[512];
    int v = (threadIdx.x < nb) ? bsum[threadIdx.x] : 0;
    s[threadIdx.x] = v;
    __syncthreads();
    for (int d = 1; d < 512; d <<= 1) {
        int t = (threadIdx.x >= (unsigned)d) ? s[threadIdx.x - d] : 0;
        __syncthreads();
        s[threadIdx.x] += t;
        __syncthreads();
    }
    if (threadIdx.x < nb) boff[threadIdx.x] = s[threadIdx.x] - v;
}

__global__ void scanC_kernel(const int* tmp, const int* __restrict__ boff,
                             int* __restrict__ off, int* cur, int m, int e_tot) {
    int i = blockIdx.x * 256 + threadIdx.x;
    if (i < m) {
        int o = tmp[i] + boff[i >> 8];
        off[i] = o;
        cur[i] = o;
    }
    if (i == 0) off[m] = e_tot;
}

__global__ void scatter4_kernel(const int* __restrict__ sub_rows, const int* __restrict__ sub_cols,
                                const float* __restrict__ sub_vals, int e_sub,
                                const int* __restrict__ sup_rows, const int* __restrict__ sup_cols,
                                const float* __restrict__ sup_vals, int e_sup,
                                int* __restrict__ cur, int2* __restrict__ pk, int nrows) {
    int i = blockIdx.x * blockDim.x + threadIdx.x;
    int e_tot = e_sub + e_sup;
    if (i >= e_tot) return;
    int r, c; float v;
    if (i < e_sub) { r = sub_rows[i]; c = sub_cols[i]; v = sub_vals[i]; }
    else { int k = i - e_sub; r = nrows + sup_rows[k]; c = sup_cols[k]; v = sup_vals[k]; }
    int pos = atomicAdd(&cur[r], 1);
    pk[pos] = make_int2(c, __float_as_int(v));
}

__global__ void row4_kernel(const int* __restrict__ off, const int2* __restrict__ pk,
                            const float* __restrict__ inputs, const float* __restrict__ old_act,
                            const int* __restrict__ fields, float* __restrict__ out, int nrows) {
    int wv = threadIdx.x >> 6, lane = threadIdx.x & 63;
    int r = blockIdx.x * (blockDim.x >> 6) + wv;
    if (r >= nrows) return;
    int d0 = lane * 2;
    float a0 = 0.f, a1 = 0.f;
    int b = off[r], e = off[r + 1];
    for (int j = b; j < e; ++j) {
        int2 p = pk[j];
        int c = p.x; float v = __int_as_float(p.y);
        int f = fields[c];
        float2 x = *(const float2*)(inputs  + (size_t)c * DIM + d0);
        float2 y = *(const float2*)(old_act + (size_t)f * DIM + d0);
        a0 += v * (x.x - y.x);
        a1 += v * (x.y - y.y);
    }
    b = off[nrows + r]; e = off[nrows + r + 1];
    for (int j = b; j < e; ++j) {
        int2 p = pk[j];
        int c = p.x; float v = __int_as_float(p.y);
        float2 y = *(const float2*)(old_act + (size_t)c * DIM + d0);
        a0 += v * y.x;
        a1 += v * y.y;
    }
    *(float2*)(out + (size_t)r * DIM + d0) = make_float2(a0, a1);
}

extern "C" void kernel_launch(void* const* d_in, const int* in_sizes, int n_in,
                              void* d_out, int out_size, void* d_ws, size_t ws_size,
                              hipStream_t stream) {
    const float* inputs   = (const float*)d_in[0];
    const float* old_act  = (const float*)d_in[1];
    const int*   fields   = (const int*)d_in[2];
    const int*   sub_rows = (const int*)d_in[3];
    const int*   sub_cols = (const int*)d_in[4];
    const float* sub_vals = (const float*)d_in[5];
    const int*   sup_rows = (const int*)d_in[6];
    const int*   sup_cols = (const int*)d_in[7];
    const float* sup_vals = (const float*)d_in[8];

    const int n     = in_sizes[0];     // BATCH * DIM
    const int nrows = n / DIM;         // BATCH
    const int e_sub = in_sizes[3];
    const int e_sup = in_sizes[6];
    const int e_tot = e_sub + e_sup;

    float* out = (float*)d_out;
    char*  ws  = (char*)d_ws;

    // ---- primary (bucket) layout ----
    size_t off_part = 0;                                                // f32[PREP_GRID*3]
    size_t off_cnt  = (PREP_GRID * 3 * 4 + 63) & ~(size_t)63;           // int[2*nrows+1]
    size_t off_over = (off_cnt + (size_t)(2 * nrows + 1) * 4 + 15) & ~(size_t)15;  // int4[OVER_MAX]
    size_t off_psub = off_over + (size_t)OVER_MAX * 16;                 // int2[nrows*SUB_CAP]
    size_t off_psup = off_psub + (size_t)nrows * SUB_CAP * 8;           // int2[nrows*SUP_CAP]
    size_t off_diff = off_psup + (size_t)nrows * SUP_CAP * 8;           // f32[n]
    size_t need_base = off_diff;
    size_t need_diff = off_diff + (size_t)n * 4;

    if (ws_size >= need_base) {
        float* partials = (float*)(ws + off_part);
        int*   cnt      = (int*)(ws + off_cnt);
        int4*  over     = (int4*)(ws + off_over);
        int2*  pk_sub   = (int2*)(ws + off_psub);
        int2*  pk_sup   = (int2*)(ws + off_psup);
        float* diff     = (float*)(ws + off_diff);
        int use_diff    = (ws_size >= need_diff) ? 1 : 0;

        hipMemsetAsync(cnt, 0, (size_t)(2 * nrows + 1) * 4, stream);

        prep_bin_kernel<<<PREP_GRID, TPB, 0, stream>>>(
            inputs, old_act, fields,
            sub_rows, sub_cols, sub_vals, e_sub,
            sup_rows, sup_cols, sup_vals, e_sup,
            cnt, pk_sub, pk_sup, over, partials, diff, use_diff, nrows, n / 2);

        row_bucket_kernel<<<(nrows + 3) / 4, TPB, 0, stream>>>(
            cnt, pk_sub, pk_sup, diff, inputs, old_act, fields, out, nrows, use_diff);

        tail_kernel<<<32, TPB, 0, stream>>>(
            partials, PREP_GRID, cnt, over, diff, inputs, old_act, fields,
            out, nrows, n, use_diff);
        return;
    }

    // ---- fallback: round-4 scan pipeline ----
    const int m     = 2 * nrows;
    const int nblkA = (m + 255) / 256;
    size_t f_part = 0;
    size_t f_cnt  = (2048 * 3 * 4 + 63) & ~(size_t)63;
    size_t f_tmp  = f_cnt + (size_t)m * 4;
    size_t f_offs = f_tmp + (size_t)m * 4;
    size_t f_bsum = f_offs + (size_t)(m + 1) * 4;
    size_t f_boff = f_bsum + 4096;
    size_t f_pk   = (f_boff + 4096 + 7) & ~(size_t)7;
    size_t f_need = f_pk + (size_t)e_tot * 8;

    float* partials = (float*)(ws + f_part);
    int*   cnt      = (int*)(ws + f_cnt);
    int*   tmp      = (int*)(ws + f_tmp);
    int*   offs     = (int*)(ws + f_offs);
    int*   bsum     = (int*)(ws + f_bsum);
    int*   boff     = (int*)(ws + f_boff);
    int2*  pk       = (int2*)(ws + f_pk);

    if (ws_size >= f_need && nblkA <= 512) {
        hipMemsetAsync(cnt, 0, (size_t)m * 4, stream);
        prep4_kernel<<<2048, 256, 0, stream>>>(inputs, old_act, fields,
                                               sub_rows, e_sub, sup_rows, e_sup,
                                               cnt, partials, nrows, n / 2);
        scanA_kernel<<<nblkA, 256, 0, stream>>>(cnt, tmp, bsum, m);
        scanB_kernel<<<1, 512, 0, stream>>>(bsum, boff, nblkA);
        scanC_kernel<<<nblkA, 256, 0, stream>>>(tmp, boff, offs, tmp, m, e_tot);
        scatter4_kernel<<<(e_tot + 255) / 256, 256, 0, stream>>>(
            sub_rows, sub_cols, sub_vals, e_sub,
            sup_rows, sup_cols, sup_vals, e_sup, tmp, pk, nrows);
        row4_kernel<<<(nrows + 3) / 4, 256, 0, stream>>>(offs, pk, inputs, old_act,
                                                         fields, out, nrows);
        finalize4_kernel<<<1, 64, 0, stream>>>(partials, 2048, out + n);
    }
}